// Round 3
// baseline (432.006 us; speedup 1.0000x reference)
//
#include <hip/hip_runtime.h>
#include <stdint.h>

typedef __attribute__((ext_vector_type(8))) short short8;
typedef __attribute__((ext_vector_type(4))) float f32x4;

// ---- problem constants ----
#define TOKENS 4096
#define DDIM 1024
#define IDIM 512
#define NEXP 16
#define NEXP1 17
#define NSLOTS 12288  // 4096 shared + 2*4096 routed

// ---- workspace layout (bytes) ----
#define OFF_WGU   0ull           // 17*1024*1024*2 = 35651584   [e][n(0..1023: g|u)][k] bf16
#define OFF_WD    35651584ull    // 17*1024*512*2  = 17825792   [e][n(D)][k(I)] bf16
#define OFF_XB    53477376ull    // 4096*1024*2    = 8388608    x in bf16
#define OFF_HGU   61865984ull    // 12288*1024*2   = 25165824   gemmA output
#define OFF_H     87031808ull    // 12288*512*2    = 12582912   silu(g)*u
#define OFF_TOK   99614720ull    // 17*4096*4      = 278528
#define OFF_WT    99893248ull    // 17*4096*4      = 278528
#define OFF_CNT   100171776ull   // 17*4 (+pad)
#define OFF_BASE  100172032ull   // 18*4
#define OFF_GWT   100173824ull   // 16*1024*4 = 65536  gate weights transposed [e][k] fp32

__device__ __forceinline__ float bf2f(unsigned short u) {
    union { uint32_t i; float f; } v; v.i = ((uint32_t)u) << 16; return v.f;
}
__device__ __forceinline__ unsigned short f2bf(float f) {
    union { float f; uint32_t i; } v; v.f = f;
    uint32_t r = v.i + 0x7FFFu + ((v.i >> 16) & 1u);  // RNE
    return (unsigned short)(r >> 16);
}

// ---- weight transpose + fp32->bf16: dst[n][k] k-contiguous ----
__global__ void k_transpose(const float* __restrict__ eg, const float* __restrict__ eu,
                            const float* __restrict__ ed, const float* __restrict__ sg,
                            const float* __restrict__ su, const float* __restrict__ sd,
                            unsigned short* __restrict__ Wgu, unsigned short* __restrict__ Wd)
{
    int z = blockIdx.z;
    int e = z / 3, m = z % 3;
    int R = (m == 2) ? 512 : 1024;   // src rows (k)
    int C = (m == 2) ? 1024 : 512;   // src cols (n)
    int r0 = blockIdx.y * 32, c0 = blockIdx.x * 32;
    if (r0 >= R || c0 >= C) return;
    const float* src;
    if (m == 0)      src = (e < 16) ? eg + (size_t)e * 524288 : sg;
    else if (m == 1) src = (e < 16) ? eu + (size_t)e * 524288 : su;
    else             src = (e < 16) ? ed + (size_t)e * 524288 : sd;

    __shared__ float tl[32][33];
    int c = threadIdx.x & 31, r = threadIdx.x >> 5;
    #pragma unroll
    for (int rr = 0; rr < 4; ++rr)
        tl[r + rr * 8][c] = src[(size_t)(r0 + r + rr * 8) * C + (c0 + c)];
    __syncthreads();
    #pragma unroll
    for (int rr = 0; rr < 4; ++rr) {
        int n = c0 + r + rr * 8;
        int k = r0 + c;
        unsigned short hv = f2bf(tl[c][r + rr * 8]);
        if (m < 2) Wgu[(size_t)e * 1048576 + (size_t)(n + (m == 1 ? 512 : 0)) * 1024 + k] = hv;
        else       Wd [(size_t)e * 524288  + (size_t)n * 512 + k] = hv;
    }
}

// ---- x -> bf16, out = x, shared-expert token list, gate-weight transpose ----
__global__ void k_xconv(const float* __restrict__ x, unsigned short* __restrict__ xb,
                        float* __restrict__ out, int* __restrict__ tok, float* __restrict__ wt,
                        const float* __restrict__ gw, float* __restrict__ gwT)
{
    int i = blockIdx.x * 256 + threadIdx.x;   // 1048576 float4 groups, exact
    float4 v = ((const float4*)x)[i];
    ((float4*)out)[i] = v;
    ushort4 b;
    b.x = f2bf(v.x); b.y = f2bf(v.y); b.z = f2bf(v.z); b.w = f2bf(v.w);
    ((ushort4*)xb)[i] = b;
    if (i < TOKENS) { tok[16 * 4096 + i] = i; wt[16 * 4096 + i] = 1.0f; }
    if (i < NEXP * DDIM) {           // gwT[e][k] = gw[k][e]  (one-time 64 KB)
        int e = i >> 10, k = i & 1023;
        gwT[i] = gw[k * 16 + e];
    }
}

// ---- router: one wave per token; coalesced gwT reads, fp64 accumulate ----
__global__ __launch_bounds__(256)
void k_router(const float* __restrict__ x, const float* __restrict__ gwT,
              const float* __restrict__ gb, int* __restrict__ tok,
              float* __restrict__ wt, int* __restrict__ counts)
{
    const int t = blockIdx.x * 4 + (threadIdx.x >> 6);   // 1024 blocks * 4 waves
    const int lane = threadIdx.x & 63;
    const float* xr = x + (size_t)t * DDIM;

    float xv[16];
    #pragma unroll
    for (int kk = 0; kk < 16; ++kk) xv[kk] = xr[kk * 64 + lane];

    float v[16];
    #pragma unroll
    for (int e = 0; e < 16; ++e) {
        const float* ge = gwT + (size_t)e * DDIM + lane;
        double a0 = 0.0, a1 = 0.0;
        #pragma unroll
        for (int kk = 0; kk < 16; kk += 2) {
            a0 += (double)xv[kk]     * (double)ge[kk * 64];
            a1 += (double)xv[kk + 1] * (double)ge[kk * 64 + 64];
        }
        double a = a0 + a1;
        #pragma unroll
        for (int off = 32; off > 0; off >>= 1)
            a += __shfl_xor(a, off, 64);
        v[e] = 1.0f / (1.0f + expf(-(float)(a + (double)gb[e])));
    }

    if (lane == 0) {
        int i0 = 0;
        #pragma unroll
        for (int e = 1; e < 16; ++e) if (v[e] > v[i0]) i0 = e;
        int i1 = (i0 == 0) ? 1 : 0;
        #pragma unroll
        for (int e = 0; e < 16; ++e) if (e != i0 && e != i1 && v[e] > v[i1]) i1 = e;
        float s = v[i0] + v[i1];
        float w0 = v[i0] / s, w1 = v[i1] / s;
        int p0 = atomicAdd(&counts[i0], 1);
        tok[i0 * 4096 + p0] = t; wt[i0 * 4096 + p0] = w0;
        int p1 = atomicAdd(&counts[i1], 1);
        tok[i1 * 4096 + p1] = t; wt[i1 * 4096 + p1] = w1;
    }
}

__global__ void k_prefix(int* counts, int* bases)
{
    if (threadIdx.x == 0 && blockIdx.x == 0) {
        counts[16] = TOKENS;
        int a = 0;
        for (int e = 0; e < NEXP1; ++e) { bases[e] = a; a += counts[e]; }
        bases[17] = a;
    }
}

// ---- grouped GEMM, 128x128 tile, 16x16x32 bf16 MFMA, 4 waves ----
// MODE 0: A = xb gathered by token_list, K=1024, B=Wgu, write Hgu (bf16)
// MODE 1: A = H (contiguous slots),     K=512,  B=Wd,  weighted atomicAdd into out
template <int MODE>
__global__ __launch_bounds__(256, 2)
void k_gemm(const unsigned short* __restrict__ Amat, const unsigned short* __restrict__ Bmat,
            const int* __restrict__ tok, const float* __restrict__ wt,
            const int* __restrict__ counts, const int* __restrict__ bases,
            unsigned short* __restrict__ Hgu, float* __restrict__ out)
{
    constexpr int K = (MODE == 0) ? 1024 : 512;
    const int e = blockIdx.z;
    const int cnt = counts[e];
    const int m0 = blockIdx.y * 128;
    if (m0 >= cnt) return;
    const int n0 = blockIdx.x * 128;
    const int base = bases[e];

    __shared__ unsigned short As[128 * 40];   // padded stride 40 -> 2-way (free) on frag reads
    __shared__ unsigned short Bs[128 * 40];

    const int tid = threadIdx.x;
    const int seg = tid & 3;      // 16B segment within 32-elem k-slab
    const int hrow = tid >> 2;    // 0..63

    const unsigned short* aptr[2];
    const unsigned short* bptr[2];
    unsigned short* asd[2];
    unsigned short* bsd[2];
    #pragma unroll
    for (int it = 0; it < 2; ++it) {
        int row = hrow + it * 64;
        int rc = m0 + row; if (rc > cnt - 1) rc = cnt - 1;
        size_t rowidx;
        if (MODE == 0) rowidx = (size_t)tok[e * 4096 + rc];
        else           rowidx = (size_t)(base + rc);
        aptr[it] = Amat + rowidx * K + seg * 8;
        bptr[it] = Bmat + (size_t)e * 1024 * K + (size_t)(n0 + row) * K + seg * 8;
        asd[it] = &As[row * 40 + seg * 8];
        bsd[it] = &Bs[row * 40 + seg * 8];
    }

    const int wave = tid >> 6;
    const int lane = tid & 63;
    const int wm = wave & 1, wn = wave >> 1;
    const int q = lane >> 4, mc = lane & 15;

    f32x4 acc[4][4];
    #pragma unroll
    for (int i = 0; i < 4; ++i)
        #pragma unroll
        for (int j = 0; j < 4; ++j) acc[i][j] = (f32x4){0.f, 0.f, 0.f, 0.f};

    for (int k0 = 0; k0 < K; k0 += 32) {
        uint4 av0 = *(const uint4*)(aptr[0] + k0);
        uint4 av1 = *(const uint4*)(aptr[1] + k0);
        uint4 bv0 = *(const uint4*)(bptr[0] + k0);
        uint4 bv1 = *(const uint4*)(bptr[1] + k0);
        __syncthreads();
        *(uint4*)asd[0] = av0;
        *(uint4*)asd[1] = av1;
        *(uint4*)bsd[0] = bv0;
        *(uint4*)bsd[1] = bv1;
        __syncthreads();
        short8 a[4], b[4];
        #pragma unroll
        for (int i = 0; i < 4; ++i)
            a[i] = *(const short8*)&As[(wm * 64 + i * 16 + mc) * 40 + q * 8];
        #pragma unroll
        for (int j = 0; j < 4; ++j)
            b[j] = *(const short8*)&Bs[(wn * 64 + j * 16 + mc) * 40 + q * 8];
        #pragma unroll
        for (int i = 0; i < 4; ++i)
            #pragma unroll
            for (int j = 0; j < 4; ++j)
                acc[i][j] = __builtin_amdgcn_mfma_f32_16x16x32_bf16(a[i], b[j], acc[i][j], 0, 0, 0);
    }

    // epilogue: C/D layout col=lane&15, row=(lane>>4)*4+reg  [m89-verified]
    #pragma unroll
    for (int i = 0; i < 4; ++i) {
        int lrow = wm * 64 + i * 16 + q * 4;
        #pragma unroll
        for (int r = 0; r < 4; ++r) {
            int mrow = m0 + lrow + r;
            if (mrow >= cnt) continue;
            if (MODE == 0) {
                size_t rowoff = (size_t)(base + mrow) * 1024;
                #pragma unroll
                for (int j = 0; j < 4; ++j) {
                    int gc = n0 + wn * 64 + j * 16 + mc;
                    Hgu[rowoff + gc] = f2bf(acc[i][j][r]);
                }
            } else {
                int t = tok[e * 4096 + mrow];
                float w = wt[e * 4096 + mrow];
                size_t rowoff = (size_t)t * 1024;
                #pragma unroll
                for (int j = 0; j < 4; ++j) {
                    int gc = n0 + wn * 64 + j * 16 + mc;
                    atomicAdd(&out[rowoff + gc], w * acc[i][j][r]);
                }
            }
        }
    }
}

// ---- H[s][i] = silu(Hgu[s][i]) * Hgu[s][i+512] ----
__global__ void k_silu(const unsigned short* __restrict__ Hgu, unsigned short* __restrict__ H)
{
    int gid = blockIdx.x * 256 + threadIdx.x;  // 786432 threads, exact
    int s = gid >> 6;
    int c = (gid & 63) * 8;
    const unsigned short* g = Hgu + (size_t)s * 1024 + c;
    unsigned short gg[8], uu[8], oo[8];
    *(uint4*)gg = *(const uint4*)g;
    *(uint4*)uu = *(const uint4*)(g + 512);
    #pragma unroll
    for (int j = 0; j < 8; ++j) {
        float gv = bf2f(gg[j]);
        float uv = bf2f(uu[j]);
        float sv = gv / (1.0f + __expf(-gv));
        oo[j] = f2bf(sv * uv);
    }
    *(uint4*)(H + (size_t)s * 512 + c) = *(uint4*)oo;
}

extern "C" void kernel_launch(void* const* d_in, const int* in_sizes, int n_in,
                              void* d_out, int out_size, void* d_ws, size_t ws_size,
                              hipStream_t stream)
{
    const float* x  = (const float*)d_in[0];
    const float* gw = (const float*)d_in[1];
    const float* gb = (const float*)d_in[2];
    const float* sg = (const float*)d_in[3];
    const float* su = (const float*)d_in[4];
    const float* sd = (const float*)d_in[5];
    const float* eg = (const float*)d_in[6];
    const float* eu = (const float*)d_in[7];
    const float* ed = (const float*)d_in[8];
    float* out = (float*)d_out;
    char* ws = (char*)d_ws;

    unsigned short* Wgu = (unsigned short*)(ws + OFF_WGU);
    unsigned short* Wd  = (unsigned short*)(ws + OFF_WD);
    unsigned short* xb  = (unsigned short*)(ws + OFF_XB);
    unsigned short* Hgu = (unsigned short*)(ws + OFF_HGU);
    unsigned short* H   = (unsigned short*)(ws + OFF_H);
    int*   tok   = (int*)(ws + OFF_TOK);
    float* wt    = (float*)(ws + OFF_WT);
    int*   counts= (int*)(ws + OFF_CNT);
    int*   bases = (int*)(ws + OFF_BASE);
    float* gwT   = (float*)(ws + OFF_GWT);

    hipMemsetAsync(counts, 0, 128, stream);
    k_transpose<<<dim3(32, 32, 51), 256, 0, stream>>>(eg, eu, ed, sg, su, sd, Wgu, Wd);
    k_xconv<<<4096, 256, 0, stream>>>(x, xb, out, tok, wt, gw, gwT);
    k_router<<<1024, 256, 0, stream>>>(x, gwT, gb, tok, wt, counts);
    k_prefix<<<1, 64, 0, stream>>>(counts, bases);
    k_gemm<0><<<dim3(8, 32, 17), 256, 0, stream>>>(xb, Wgu, tok, wt, counts, bases, Hgu, out);
    k_silu<<<3072, 256, 0, stream>>>(Hgu, H);
    k_gemm<1><<<dim3(8, 32, 17), 256, 0, stream>>>(H, Wd, tok, wt, counts, bases, Hgu, out);
}

// Round 4
// 398.933 us; speedup vs baseline: 1.0829x; 1.0829x over previous
//
#include <hip/hip_runtime.h>
#include <stdint.h>

typedef __attribute__((ext_vector_type(8))) short short8;
typedef __attribute__((ext_vector_type(4))) float f32x4;

// ---- problem constants ----
#define TOKENS 4096
#define DDIM 1024
#define IDIM 512
#define NEXP 16
#define NEXP1 17
#define NSLOTS 12288  // 4096 shared + 2*4096 routed

// ---- workspace layout (bytes) ----
#define OFF_WGU   0ull           // 17*1024*1024*2 = 35651584   [e][n(0..1023: g|u)][k] bf16
#define OFF_WD    35651584ull    // 17*1024*512*2  = 17825792   [e][n(D)][k(I)] bf16
#define OFF_XB    53477376ull    // 4096*1024*2    = 8388608    x in bf16
#define OFF_HGU   61865984ull    // 12288*1024*2   = 25165824   gemmA output
#define OFF_H     87031808ull    // 12288*512*2    = 12582912   silu(g)*u
#define OFF_TOK   99614720ull    // 17*4096*4      = 278528
#define OFF_WT    99893248ull    // 17*4096*4      = 278528
#define OFF_CNT   100171776ull   // 17*4 (+pad)
#define OFF_BASE  100172032ull   // 18*4

__device__ __forceinline__ float bf2f(unsigned short u) {
    union { uint32_t i; float f; } v; v.i = ((uint32_t)u) << 16; return v.f;
}
__device__ __forceinline__ unsigned short f2bf(float f) {
    union { float f; uint32_t i; } v; v.f = f;
    uint32_t r = v.i + 0x7FFFu + ((v.i >> 16) & 1u);  // RNE
    return (unsigned short)(r >> 16);
}

// ---- weight transpose + fp32->bf16: dst[n][k] k-contiguous ----
__global__ void k_transpose(const float* __restrict__ eg, const float* __restrict__ eu,
                            const float* __restrict__ ed, const float* __restrict__ sg,
                            const float* __restrict__ su, const float* __restrict__ sd,
                            unsigned short* __restrict__ Wgu, unsigned short* __restrict__ Wd)
{
    int z = blockIdx.z;
    int e = z / 3, m = z % 3;
    int R = (m == 2) ? 512 : 1024;   // src rows (k)
    int C = (m == 2) ? 1024 : 512;   // src cols (n)
    int r0 = blockIdx.y * 32, c0 = blockIdx.x * 32;
    if (r0 >= R || c0 >= C) return;
    const float* src;
    if (m == 0)      src = (e < 16) ? eg + (size_t)e * 524288 : sg;
    else if (m == 1) src = (e < 16) ? eu + (size_t)e * 524288 : su;
    else             src = (e < 16) ? ed + (size_t)e * 524288 : sd;

    __shared__ float tl[32][33];
    int c = threadIdx.x & 31, r = threadIdx.x >> 5;
    #pragma unroll
    for (int rr = 0; rr < 4; ++rr)
        tl[r + rr * 8][c] = src[(size_t)(r0 + r + rr * 8) * C + (c0 + c)];
    __syncthreads();
    #pragma unroll
    for (int rr = 0; rr < 4; ++rr) {
        int n = c0 + r + rr * 8;
        int k = r0 + c;
        unsigned short hv = f2bf(tl[c][r + rr * 8]);
        if (m < 2) Wgu[(size_t)e * 1048576 + (size_t)(n + (m == 1 ? 512 : 0)) * 1024 + k] = hv;
        else       Wd [(size_t)e * 524288  + (size_t)n * 512 + k] = hv;
    }
}

// ---- x -> bf16, out = x, fill shared-expert token list ----
__global__ void k_xconv(const float* __restrict__ x, unsigned short* __restrict__ xb,
                        float* __restrict__ out, int* __restrict__ tok, float* __restrict__ wt)
{
    int i = blockIdx.x * 256 + threadIdx.x;   // 1048576 float4 groups, exact
    float4 v = ((const float4*)x)[i];
    ((float4*)out)[i] = v;
    ushort4 b;
    b.x = f2bf(v.x); b.y = f2bf(v.y); b.z = f2bf(v.z); b.w = f2bf(v.w);
    ((ushort4*)xb)[i] = b;
    if (i < TOKENS) { tok[16 * 4096 + i] = i; wt[16 * 4096 + i] = 1.0f; }
}

// ---- router: gw staged in LDS (17-stride, conflict-free), one wave per token,
//      16 independent fp64 chains per lane, single butterfly at the end ----
__global__ __launch_bounds__(512, 4)
void k_router(const float* __restrict__ x, const float* __restrict__ gw,
              const float* __restrict__ gb, int* __restrict__ tok,
              float* __restrict__ wt, int* __restrict__ counts)
{
    __shared__ float gws[512 * 17];              // half of gw per phase, padded rows

    const int t = blockIdx.x * 8 + (threadIdx.x >> 6);   // 512 blocks * 8 waves
    const int lane = threadIdx.x & 63;
    const float* xr = x + (size_t)t * DDIM;

    float xv[16];
    #pragma unroll
    for (int kk = 0; kk < 16; ++kk) xv[kk] = xr[kk * 64 + lane];

    double acc[16];
    #pragma unroll
    for (int e = 0; e < 16; ++e) acc[e] = 0.0;

    for (int p = 0; p < 2; ++p) {
        __syncthreads();
        // stage 512 rows x 16 floats (2048 float4), 4 float4 per thread, coalesced
        #pragma unroll
        for (int c = 0; c < 4; ++c) {
            int idx = threadIdx.x + c * 512;          // 0..2047
            float4 v = ((const float4*)gw)[p * 2048 + idx];
            int kl = idx >> 2, e4 = (idx & 3) * 4;
            float* d = &gws[kl * 17 + e4];
            d[0] = v.x; d[1] = v.y; d[2] = v.z; d[3] = v.w;
        }
        __syncthreads();
        #pragma unroll
        for (int kk = 0; kk < 8; ++kk) {
            int kl = kk * 64 + lane;
            double xd = (double)xv[p * 8 + kk];
            const float* g = &gws[kl * 17];
            #pragma unroll
            for (int e = 0; e < 16; ++e)
                acc[e] += xd * (double)g[e];
        }
    }

    // single butterfly: 6 levels, 16 independent chains per level
    #pragma unroll
    for (int off = 32; off > 0; off >>= 1) {
        #pragma unroll
        for (int e = 0; e < 16; ++e)
            acc[e] += __shfl_xor(acc[e], off, 64);
    }

    if (lane == 0) {
        float v[16];
        #pragma unroll
        for (int e = 0; e < 16; ++e)
            v[e] = 1.0f / (1.0f + expf(-(float)(acc[e] + (double)gb[e])));
        int i0 = 0;
        #pragma unroll
        for (int e = 1; e < 16; ++e) if (v[e] > v[i0]) i0 = e;
        int i1 = (i0 == 0) ? 1 : 0;
        #pragma unroll
        for (int e = 0; e < 16; ++e) if (e != i0 && e != i1 && v[e] > v[i1]) i1 = e;
        float s = v[i0] + v[i1];
        float w0 = v[i0] / s, w1 = v[i1] / s;
        int p0 = atomicAdd(&counts[i0], 1);
        tok[i0 * 4096 + p0] = t; wt[i0 * 4096 + p0] = w0;
        int p1 = atomicAdd(&counts[i1], 1);
        tok[i1 * 4096 + p1] = t; wt[i1 * 4096 + p1] = w1;
    }
}

__global__ void k_prefix(int* counts, int* bases)
{
    if (threadIdx.x == 0 && blockIdx.x == 0) {
        counts[16] = TOKENS;
        int a = 0;
        for (int e = 0; e < NEXP1; ++e) { bases[e] = a; a += counts[e]; }
        bases[17] = a;
    }
}

// ---- grouped GEMM, 128x128 tile, 16x16x32 bf16 MFMA, 4 waves ----
// MODE 0: A = xb gathered by token_list, K=1024, B=Wgu, write Hgu (bf16)
// MODE 1: A = H (contiguous slots),     K=512,  B=Wd,  weighted atomicAdd into out
template <int MODE>
__global__ __launch_bounds__(256, 2)
void k_gemm(const unsigned short* __restrict__ Amat, const unsigned short* __restrict__ Bmat,
            const int* __restrict__ tok, const float* __restrict__ wt,
            const int* __restrict__ counts, const int* __restrict__ bases,
            unsigned short* __restrict__ Hgu, float* __restrict__ out)
{
    constexpr int K = (MODE == 0) ? 1024 : 512;
    const int e = blockIdx.z;
    const int cnt = counts[e];
    const int m0 = blockIdx.y * 128;
    if (m0 >= cnt) return;
    const int n0 = blockIdx.x * 128;
    const int base = bases[e];

    __shared__ unsigned short As[128 * 40];   // padded stride 40 -> 2-way (free) on frag reads
    __shared__ unsigned short Bs[128 * 40];

    const int tid = threadIdx.x;
    const int seg = tid & 3;      // 16B segment within 32-elem k-slab
    const int hrow = tid >> 2;    // 0..63

    const unsigned short* aptr[2];
    const unsigned short* bptr[2];
    unsigned short* asd[2];
    unsigned short* bsd[2];
    #pragma unroll
    for (int it = 0; it < 2; ++it) {
        int row = hrow + it * 64;
        int rc = m0 + row; if (rc > cnt - 1) rc = cnt - 1;
        size_t rowidx;
        if (MODE == 0) rowidx = (size_t)tok[e * 4096 + rc];
        else           rowidx = (size_t)(base + rc);
        aptr[it] = Amat + rowidx * K + seg * 8;
        bptr[it] = Bmat + (size_t)e * 1024 * K + (size_t)(n0 + row) * K + seg * 8;
        asd[it] = &As[row * 40 + seg * 8];
        bsd[it] = &Bs[row * 40 + seg * 8];
    }

    const int wave = tid >> 6;
    const int lane = tid & 63;
    const int wm = wave & 1, wn = wave >> 1;
    const int q = lane >> 4, mc = lane & 15;

    f32x4 acc[4][4];
    #pragma unroll
    for (int i = 0; i < 4; ++i)
        #pragma unroll
        for (int j = 0; j < 4; ++j) acc[i][j] = (f32x4){0.f, 0.f, 0.f, 0.f};

    for (int k0 = 0; k0 < K; k0 += 32) {
        uint4 av0 = *(const uint4*)(aptr[0] + k0);
        uint4 av1 = *(const uint4*)(aptr[1] + k0);
        uint4 bv0 = *(const uint4*)(bptr[0] + k0);
        uint4 bv1 = *(const uint4*)(bptr[1] + k0);
        __syncthreads();
        *(uint4*)asd[0] = av0;
        *(uint4*)asd[1] = av1;
        *(uint4*)bsd[0] = bv0;
        *(uint4*)bsd[1] = bv1;
        __syncthreads();
        short8 a[4], b[4];
        #pragma unroll
        for (int i = 0; i < 4; ++i)
            a[i] = *(const short8*)&As[(wm * 64 + i * 16 + mc) * 40 + q * 8];
        #pragma unroll
        for (int j = 0; j < 4; ++j)
            b[j] = *(const short8*)&Bs[(wn * 64 + j * 16 + mc) * 40 + q * 8];
        #pragma unroll
        for (int i = 0; i < 4; ++i)
            #pragma unroll
            for (int j = 0; j < 4; ++j)
                acc[i][j] = __builtin_amdgcn_mfma_f32_16x16x32_bf16(a[i], b[j], acc[i][j], 0, 0, 0);
    }

    // epilogue: C/D layout col=lane&15, row=(lane>>4)*4+reg  [m89-verified]
    #pragma unroll
    for (int i = 0; i < 4; ++i) {
        int lrow = wm * 64 + i * 16 + q * 4;
        #pragma unroll
        for (int r = 0; r < 4; ++r) {
            int mrow = m0 + lrow + r;
            if (mrow >= cnt) continue;
            if (MODE == 0) {
                size_t rowoff = (size_t)(base + mrow) * 1024;
                #pragma unroll
                for (int j = 0; j < 4; ++j) {
                    int gc = n0 + wn * 64 + j * 16 + mc;
                    Hgu[rowoff + gc] = f2bf(acc[i][j][r]);
                }
            } else {
                int t = tok[e * 4096 + mrow];
                float w = wt[e * 4096 + mrow];
                size_t rowoff = (size_t)t * 1024;
                #pragma unroll
                for (int j = 0; j < 4; ++j) {
                    int gc = n0 + wn * 64 + j * 16 + mc;
                    atomicAdd(&out[rowoff + gc], w * acc[i][j][r]);
                }
            }
        }
    }
}

// ---- H[s][i] = silu(Hgu[s][i]) * Hgu[s][i+512] ----
__global__ void k_silu(const unsigned short* __restrict__ Hgu, unsigned short* __restrict__ H)
{
    int gid = blockIdx.x * 256 + threadIdx.x;  // 786432 threads, exact
    int s = gid >> 6;
    int c = (gid & 63) * 8;
    const unsigned short* g = Hgu + (size_t)s * 1024 + c;
    unsigned short gg[8], uu[8], oo[8];
    *(uint4*)gg = *(const uint4*)g;
    *(uint4*)uu = *(const uint4*)(g + 512);
    #pragma unroll
    for (int j = 0; j < 8; ++j) {
        float gv = bf2f(gg[j]);
        float uv = bf2f(uu[j]);
        float sv = gv / (1.0f + __expf(-gv));
        oo[j] = f2bf(sv * uv);
    }
    *(uint4*)(H + (size_t)s * 512 + c) = *(uint4*)oo;
}

extern "C" void kernel_launch(void* const* d_in, const int* in_sizes, int n_in,
                              void* d_out, int out_size, void* d_ws, size_t ws_size,
                              hipStream_t stream)
{
    const float* x  = (const float*)d_in[0];
    const float* gw = (const float*)d_in[1];
    const float* gb = (const float*)d_in[2];
    const float* sg = (const float*)d_in[3];
    const float* su = (const float*)d_in[4];
    const float* sd = (const float*)d_in[5];
    const float* eg = (const float*)d_in[6];
    const float* eu = (const float*)d_in[7];
    const float* ed = (const float*)d_in[8];
    float* out = (float*)d_out;
    char* ws = (char*)d_ws;

    unsigned short* Wgu = (unsigned short*)(ws + OFF_WGU);
    unsigned short* Wd  = (unsigned short*)(ws + OFF_WD);
    unsigned short* xb  = (unsigned short*)(ws + OFF_XB);
    unsigned short* Hgu = (unsigned short*)(ws + OFF_HGU);
    unsigned short* H   = (unsigned short*)(ws + OFF_H);
    int*   tok   = (int*)(ws + OFF_TOK);
    float* wt    = (float*)(ws + OFF_WT);
    int*   counts= (int*)(ws + OFF_CNT);
    int*   bases = (int*)(ws + OFF_BASE);

    hipMemsetAsync(counts, 0, 128, stream);
    k_transpose<<<dim3(32, 32, 51), 256, 0, stream>>>(eg, eu, ed, sg, su, sd, Wgu, Wd);
    k_xconv<<<4096, 256, 0, stream>>>(x, xb, out, tok, wt);
    k_router<<<512, 512, 0, stream>>>(x, gw, gb, tok, wt, counts);
    k_prefix<<<1, 64, 0, stream>>>(counts, bases);
    k_gemm<0><<<dim3(8, 32, 17), 256, 0, stream>>>(xb, Wgu, tok, wt, counts, bases, Hgu, out);
    k_silu<<<3072, 256, 0, stream>>>(Hgu, H);
    k_gemm<1><<<dim3(8, 32, 17), 256, 0, stream>>>(H, Wd, tok, wt, counts, bases, Hgu, out);
}